// Round 1
// baseline (816.030 us; speedup 1.0000x reference)
//
#include <hip/hip_runtime.h>
#include <math.h>

#define DEVI __device__ __forceinline__

DEVI float sigm(float x){ return 1.f/(1.f+__expf(-x)); }

// ---- block-wide (256 thr) reduction of two sums --------------------------
DEVI void blockReduce2(float& s1, float& s2, float* red){
    #pragma unroll
    for (int m=1;m<64;m<<=1){ s1+=__shfl_xor(s1,m); s2+=__shfl_xor(s2,m); }
    const int w = threadIdx.x>>6;
    if ((threadIdx.x&63)==0){ red[w]=s1; red[8+w]=s2; }
    __syncthreads();
    s1 = red[0]+red[1]+red[2]+red[3];
    s2 = red[8]+red[9]+red[10]+red[11];
}

// ---- generic row LayerNorm ----------------------------------------------
__global__ __launch_bounds__(256) void ln_rows(const float* __restrict__ in,
                                               const float* __restrict__ g,
                                               const float* __restrict__ bt,
                                               float* __restrict__ out, int C){
    __shared__ float red[16];
    const size_t row = blockIdx.x;
    const float* x = in + row*(size_t)C;
    float s1=0.f, s2=0.f;
    for (int c=threadIdx.x; c<C; c+=256){ float v=x[c]; s1+=v; s2+=v*v; }
    blockReduce2(s1,s2,red);
    const float inv = 1.f/(float)C;
    const float mu = s1*inv;
    const float rs = rsqrtf(s2*inv - mu*mu + 1e-5f);
    float* o = out + row*(size_t)C;
    for (int c=threadIdx.x; c<C; c+=256){
        float y = (x[c]-mu)*rs;
        if (g)  y *= g[c];
        if (bt) y += bt[c];
        o[c] = y;
    }
}

// ---- tiled f32 GEMM: C(MxN) = A(MxK) @ B(KxN), 64x64 tile, BK=16 --------
// MODE 0: C = A@B (+bias)          MODE 1: C = resid + (A@B)*mask[m]
// MODE 2: C = resid + sigmoid(gather*mask)*(A@B)*mask[m]
template<int MODE>
__global__ __launch_bounds__(256) void gemm_t(
    const float* __restrict__ A, int lda,
    const float* __restrict__ B, int ldb,
    float* __restrict__ C, int ldc,
    int M, int N, int K,
    const float* __restrict__ bias,
    const float* __restrict__ resid,
    const float* __restrict__ mask,
    const float* __restrict__ gsrc,
    const int* __restrict__ idxp)
{
    __shared__ float As[16][68];
    __shared__ float Bs[16][68];
    const int t = threadIdx.x;
    const int tx = t & 15, ty = t >> 4;
    const int bm = blockIdx.x * 64, bn = blockIdx.y * 64;
    const int am = t >> 2, akq = (t & 3) * 4;
    const int bk = t >> 4, bnq = (t & 15) * 4;
    float acc[4][4] = {};
    for (int kt = 0; kt < K; kt += 16) {
        const float4 va = *(const float4*)&A[(size_t)(bm+am)*lda + kt + akq];
        const float4 vb = *(const float4*)&B[(size_t)(kt+bk)*ldb + bn + bnq];
        As[akq+0][am]=va.x; As[akq+1][am]=va.y; As[akq+2][am]=va.z; As[akq+3][am]=va.w;
        *(float4*)&Bs[bk][bnq] = vb;
        __syncthreads();
        #pragma unroll
        for (int kk=0; kk<16; ++kk){
            const float4 af = *(const float4*)&As[kk][ty*4];
            const float4 bf = *(const float4*)&Bs[kk][tx*4];
            acc[0][0]+=af.x*bf.x; acc[0][1]+=af.x*bf.y; acc[0][2]+=af.x*bf.z; acc[0][3]+=af.x*bf.w;
            acc[1][0]+=af.y*bf.x; acc[1][1]+=af.y*bf.y; acc[1][2]+=af.y*bf.z; acc[1][3]+=af.y*bf.w;
            acc[2][0]+=af.z*bf.x; acc[2][1]+=af.z*bf.y; acc[2][2]+=af.z*bf.z; acc[2][3]+=af.z*bf.w;
            acc[3][0]+=af.w*bf.x; acc[3][1]+=af.w*bf.y; acc[3][2]+=af.w*bf.z; acc[3][3]+=af.w*bf.w;
        }
        __syncthreads();
    }
    #pragma unroll
    for (int i=0;i<4;++i){
        const int m = bm + ty*4 + i;
        #pragma unroll
        for (int jj=0;jj<4;++jj){
            const int n = bn + tx*4 + jj;
            float v = acc[i][jj];
            if (MODE==0){
                if (bias) v += bias[n];
                C[(size_t)m*ldc+n] = v;
            } else if (MODE==1){
                const float mi = mask[m];
                C[(size_t)m*ldc+n] = resid[(size_t)m*256+n] + v*mi;
            } else {
                const float mi = mask[m];
                const int id = idxp[m];
                const int bbi = m >> 10;
                const float cg = gsrc[((size_t)(bbi*256+id))*256 + n]*mi;
                C[(size_t)m*ldc+n] = resid[(size_t)m*256+n] + sigm(cg)*v*mi;
            }
        }
    }
}

// ---- dual-B GEMM: bmid = silu(A@B1) * (A@B2) ----------------------------
__global__ __launch_bounds__(256) void gemm_dual(
    const float* __restrict__ A, int lda,
    const float* __restrict__ B1, const float* __restrict__ B2, int ldb,
    float* __restrict__ C, int ldc,
    int M, int N, int K)
{
    __shared__ float As[16][68];
    __shared__ float B1s[16][68];
    __shared__ float B2s[16][68];
    const int t = threadIdx.x;
    const int tx = t & 15, ty = t >> 4;
    const int bm = blockIdx.x * 64, bn = blockIdx.y * 64;
    const int am = t >> 2, akq = (t & 3) * 4;
    const int bk = t >> 4, bnq = (t & 15) * 4;
    float acc1[4][4] = {};
    float acc2[4][4] = {};
    for (int kt = 0; kt < K; kt += 16) {
        const float4 va  = *(const float4*)&A [(size_t)(bm+am)*lda + kt + akq];
        const float4 vb1 = *(const float4*)&B1[(size_t)(kt+bk)*ldb + bn + bnq];
        const float4 vb2 = *(const float4*)&B2[(size_t)(kt+bk)*ldb + bn + bnq];
        As[akq+0][am]=va.x; As[akq+1][am]=va.y; As[akq+2][am]=va.z; As[akq+3][am]=va.w;
        *(float4*)&B1s[bk][bnq] = vb1;
        *(float4*)&B2s[bk][bnq] = vb2;
        __syncthreads();
        #pragma unroll
        for (int kk=0; kk<16; ++kk){
            const float4 af = *(const float4*)&As[kk][ty*4];
            const float4 b1 = *(const float4*)&B1s[kk][tx*4];
            const float4 b2 = *(const float4*)&B2s[kk][tx*4];
            acc1[0][0]+=af.x*b1.x; acc1[0][1]+=af.x*b1.y; acc1[0][2]+=af.x*b1.z; acc1[0][3]+=af.x*b1.w;
            acc1[1][0]+=af.y*b1.x; acc1[1][1]+=af.y*b1.y; acc1[1][2]+=af.y*b1.z; acc1[1][3]+=af.y*b1.w;
            acc1[2][0]+=af.z*b1.x; acc1[2][1]+=af.z*b1.y; acc1[2][2]+=af.z*b1.z; acc1[2][3]+=af.z*b1.w;
            acc1[3][0]+=af.w*b1.x; acc1[3][1]+=af.w*b1.y; acc1[3][2]+=af.w*b1.z; acc1[3][3]+=af.w*b1.w;
            acc2[0][0]+=af.x*b2.x; acc2[0][1]+=af.x*b2.y; acc2[0][2]+=af.x*b2.z; acc2[0][3]+=af.x*b2.w;
            acc2[1][0]+=af.y*b2.x; acc2[1][1]+=af.y*b2.y; acc2[1][2]+=af.y*b2.z; acc2[1][3]+=af.y*b2.w;
            acc2[2][0]+=af.z*b2.x; acc2[2][1]+=af.z*b2.y; acc2[2][2]+=af.z*b2.z; acc2[2][3]+=af.z*b2.w;
            acc2[3][0]+=af.w*b2.x; acc2[3][1]+=af.w*b2.y; acc2[3][2]+=af.w*b2.z; acc2[3][3]+=af.w*b2.w;
        }
        __syncthreads();
    }
    #pragma unroll
    for (int i=0;i<4;++i){
        const int m = bm + ty*4 + i;
        #pragma unroll
        for (int jj=0;jj<4;++jj){
            const int n = bn + tx*4 + jj;
            const float u1 = acc1[i][jj];
            C[(size_t)m*ldc+n] = u1*sigm(u1)*acc2[i][jj];
        }
    }
}

// ---- fused attention: 2 query rows per block -----------------------------
// qkvg row layout: [q 0..255 | k 256..511 | v 512..767 | gate_pre 768..1023]
__global__ __launch_bounds__(256) void attn_fused(
    const float* __restrict__ qkvg,
    const float* __restrict__ fp,
    const float* __restrict__ lnzg, const float* __restrict__ lnzb,
    const float* __restrict__ wbias,
    const float* __restrict__ mask,
    float* __restrict__ og)
{
    __shared__ float Ls[2][8][1024];
    __shared__ float Qs[2][256];
    __shared__ float wbs[512];
    __shared__ float2 lglb[64];
    __shared__ float denom[2][8];
    const int t = threadIdx.x;
    const int r0 = blockIdx.x*2, r1 = r0+1;
    const int b = r0 >> 10;
    Qs[0][t] = qkvg[(size_t)r0*1024 + t];
    Qs[1][t] = qkvg[(size_t)r1*1024 + t];
    wbs[t]     = wbias[t];
    wbs[256+t] = wbias[256+t];
    if (t < 64) lglb[t] = make_float2(lnzg[t], lnzb[t]);
    __syncthreads();
    const float mi0 = mask[r0], mi1 = mask[r1];
    const int h = t >> 5, jl = t & 31;

    // Phase A1: QK^T
    float q0r[32], q1r[32];
    #pragma unroll
    for (int d4=0; d4<8; ++d4){
        const float4 a = *(const float4*)&Qs[0][h*32 + d4*4];
        q0r[d4*4+0]=a.x; q0r[d4*4+1]=a.y; q0r[d4*4+2]=a.z; q0r[d4*4+3]=a.w;
        const float4 c = *(const float4*)&Qs[1][h*32 + d4*4];
        q1r[d4*4+0]=c.x; q1r[d4*4+1]=c.y; q1r[d4*4+2]=c.z; q1r[d4*4+3]=c.w;
    }
    const float scale = 0.17677669529663687f; // 1/sqrt(32)
    for (int jt=0; jt<1024; jt+=32){
        const int j = jt + jl;
        const float* krow = qkvg + ((size_t)((b<<10)+j))*1024 + 256 + h*32;
        float a0=0.f, a1=0.f;
        #pragma unroll
        for (int d4=0; d4<8; ++d4){
            const float4 k4 = *(const float4*)(krow + d4*4);
            a0 += q0r[d4*4+0]*k4.x + q0r[d4*4+1]*k4.y + q0r[d4*4+2]*k4.z + q0r[d4*4+3]*k4.w;
            a1 += q1r[d4*4+0]*k4.x + q1r[d4*4+1]*k4.y + q1r[d4*4+2]*k4.z + q1r[d4*4+3]*k4.w;
        }
        Ls[0][h][j] = a0*scale;
        Ls[1][h][j] = a1*scale;
    }
    __syncthreads();

    // Phase A2: pair-bias LN + Wbias + mask term (framepair streamed per-thread)
    #pragma unroll 1
    for (int ii=0; ii<2; ++ii){
        const float mii = ii ? mi1 : mi0;
        const size_t fpbase = (size_t)(r0+ii)*1024*64;
        #pragma unroll 1
        for (int jt=0; jt<1024; jt+=256){
            const int j = jt + t;
            const float* fprow = fp + fpbase + (size_t)j*64;
            float vv[64];
            float s1 = 0.f;
            #pragma unroll
            for (int c4=0;c4<16;++c4){
                const float4 f4 = *(const float4*)(fprow + c4*4);
                vv[c4*4+0]=f4.x; vv[c4*4+1]=f4.y; vv[c4*4+2]=f4.z; vv[c4*4+3]=f4.w;
                s1 += f4.x+f4.y+f4.z+f4.w;
            }
            const float mu = s1*(1.f/64.f);
            float s2=0.f;
            #pragma unroll
            for (int c=0;c<64;++c){ const float d=vv[c]-mu; vv[c]=d; s2+=d*d; }
            const float rs = rsqrtf(s2*(1.f/64.f)+1e-5f);
            float pb[8] = {};
            #pragma unroll
            for (int c=0;c<64;++c){
                const float2 gb2 = lglb[c];
                const float lnv = vv[c]*rs*gb2.x + gb2.y;
                const float4 w0 = *(const float4*)&wbs[c*8];
                const float4 w1 = *(const float4*)&wbs[c*8+4];
                pb[0]+=lnv*w0.x; pb[1]+=lnv*w0.y; pb[2]+=lnv*w0.z; pb[3]+=lnv*w0.w;
                pb[4]+=lnv*w1.x; pb[5]+=lnv*w1.y; pb[6]+=lnv*w1.z; pb[7]+=lnv*w1.w;
            }
            const float mterm = (mii*mask[(b<<10)+j]-1.f)*100000.f;
            #pragma unroll
            for (int hh=0; hh<8; ++hh) Ls[ii][hh][j] += pb[hh] + mterm;
        }
    }
    __syncthreads();

    // Phase B: per-head softmax (32 lanes per head)
    #pragma unroll 1
    for (int ii=0; ii<2; ++ii){
        float mx = -3.4e38f;
        for (int jj=jl; jj<1024; jj+=32) mx = fmaxf(mx, Ls[ii][h][jj]);
        #pragma unroll
        for (int off=16; off>0; off>>=1) mx = fmaxf(mx, __shfl_xor(mx, off, 32));
        float sum = 0.f;
        for (int jj=jl; jj<1024; jj+=32){
            const float e = __expf(Ls[ii][h][jj]-mx);
            Ls[ii][h][jj] = e;
            sum += e;
        }
        #pragma unroll
        for (int off=16; off>0; off>>=1) sum += __shfl_xor(sum, off, 32);
        if (jl==0) denom[ii][h] = sum;
    }
    __syncthreads();

    // Phase C: PV + gate epilogue
    float o0=0.f, o1=0.f;
    const float* vcol = qkvg + ((size_t)(b<<10))*1024 + 512 + t;
    #pragma unroll 2
    for (int j=0; j<1024; j+=4){
        const float4 p0 = *(const float4*)&Ls[0][h][j];
        const float4 p1 = *(const float4*)&Ls[1][h][j];
        const float v0 = vcol[(size_t)(j+0)*1024];
        const float v1 = vcol[(size_t)(j+1)*1024];
        const float v2 = vcol[(size_t)(j+2)*1024];
        const float v3 = vcol[(size_t)(j+3)*1024];
        o0 += p0.x*v0 + p0.y*v1 + p0.z*v2 + p0.w*v3;
        o1 += p1.x*v0 + p1.y*v1 + p1.z*v2 + p1.w*v3;
    }
    const float g0 = qkvg[(size_t)r0*1024 + 768 + t];
    const float g1 = qkvg[(size_t)r1*1024 + 768 + t];
    og[(size_t)r0*256 + t] = (o0/denom[0][h]) * sigm(g0);
    og[(size_t)r1*256 + t] = (o1/denom[1][h]) * sigm(g1);
}

// ---- sa = LN(rig)*sigmoid(cond_gate) + cond_bias -------------------------
__global__ __launch_bounds__(256) void sa_kernel(
    const float* __restrict__ rig,
    const float* __restrict__ c1res,
    const float* __restrict__ cbres,
    const int* __restrict__ idxp,
    const float* __restrict__ mask,
    float* __restrict__ sa)
{
    __shared__ float red[16];
    const int m = blockIdx.x;
    const int t = threadIdx.x;
    const float v = rig[(size_t)m*256 + t];
    float s1 = v, s2 = v*v;
    blockReduce2(s1,s2,red);
    const float mu = s1*(1.f/256.f);
    const float rs = rsqrtf(s2*(1.f/256.f) - mu*mu + 1e-5f);
    const float sn = (v-mu)*rs;
    const float mi = mask[m];
    const int id = idxp[m];
    const int b = m >> 10;
    const size_t go = ((size_t)(b*256+id))*256 + t;
    const float cgate = c1res[go]*mi;
    const float cb    = cbres[go]*mi;
    sa[(size_t)m*256+t] = sn*sigm(cgate) + cb;
}

extern "C" void kernel_launch(void* const* d_in, const int* in_sizes, int n_in,
                              void* d_out, int out_size, void* d_ws, size_t ws_size,
                              hipStream_t stream)
{
    (void)in_sizes; (void)n_in; (void)out_size; (void)ws_size;
    const float* s_     = (const float*)d_in[0];
    const float* rigids = (const float*)d_in[1];
    const float* fp     = (const float*)d_in[2];
    const float* maskp  = (const float*)d_in[3];
    const int*   idxp   = (const int*)d_in[4];
    const float* ln_g   = (const float*)d_in[5];
    const float* ln_b   = (const float*)d_in[6];
    const float* Wq     = (const float*)d_in[7];
    const float* Wkv    = (const float*)d_in[8];
    const float* lnz_g  = (const float*)d_in[9];
    const float* lnz_b  = (const float*)d_in[10];
    const float* Wbias  = (const float*)d_in[11];
    const float* Wg     = (const float*)d_in[12];
    const float* Wo     = (const float*)d_in[13];
    const float* lncond = (const float*)d_in[14];
    const float* Wc1    = (const float*)d_in[15];
    const float* bc1    = (const float*)d_in[16];
    const float* Wcn    = (const float*)d_in[17];
    const float* W1     = (const float*)d_in[18];
    const float* W2     = (const float*)d_in[19];
    const float* Wc2    = (const float*)d_in[20];
    const float* bc2    = (const float*)d_in[21];
    const float* Wb     = (const float*)d_in[22];
    float* out = (float*)d_out;

    float* ws    = (float*)d_ws;
    float* x     = ws;                  // 2048*256
    float* qkvg  = x     + 524288;      // 2048*1024
    float* ogb   = qkvg  + 2097152;     // 2048*256
    float* rig   = ogb   + 524288;      // 2048*256
    float* cn    = rig   + 524288;      // 512*384
    float* c1res = cn    + 196608;      // 512*256
    float* cbres = c1res + 131072;      // 512*256
    float* cgres = cbres + 131072;      // 512*256
    float* sab   = cgres + 131072;      // 2048*256
    float* bmid  = sab   + 524288;      // 2048*512
    // total 5,832,704 floats = ~23.3 MB of d_ws

    ln_rows<<<2048,256,0,stream>>>(rigids, ln_g, ln_b, x, 256);
    gemm_t<0><<<dim3(32,4),256,0,stream>>>(x,256, Wq,256,  qkvg,     1024, 2048,256,256, nullptr,nullptr,nullptr,nullptr,nullptr);
    gemm_t<0><<<dim3(32,8),256,0,stream>>>(x,256, Wkv,512, qkvg+256, 1024, 2048,512,256, nullptr,nullptr,nullptr,nullptr,nullptr);
    gemm_t<0><<<dim3(32,4),256,0,stream>>>(x,256, Wg,256,  qkvg+768, 1024, 2048,256,256, nullptr,nullptr,nullptr,nullptr,nullptr);
    attn_fused<<<1024,256,0,stream>>>(qkvg, fp, lnz_g, lnz_b, Wbias, maskp, ogb);
    gemm_t<1><<<dim3(32,4),256,0,stream>>>(ogb,256, Wo,256, rig,256, 2048,256,256, nullptr, rigids, maskp, nullptr,nullptr);
    ln_rows<<<512,256,0,stream>>>(s_, lncond, nullptr, cn, 384);
    gemm_t<0><<<dim3(8,4),256,0,stream>>>(cn,384, Wc1,256, c1res,256, 512,256,384, bc1,    nullptr,nullptr,nullptr,nullptr);
    gemm_t<0><<<dim3(8,4),256,0,stream>>>(cn,384, Wcn,256, cbres,256, 512,256,384, nullptr,nullptr,nullptr,nullptr,nullptr);
    gemm_t<0><<<dim3(8,4),256,0,stream>>>(s_,384, Wc2,256, cgres,256, 512,256,384, bc2,    nullptr,nullptr,nullptr,nullptr);
    sa_kernel<<<2048,256,0,stream>>>(rig, c1res, cbres, idxp, maskp, sab);
    gemm_dual<<<dim3(32,8),256,0,stream>>>(sab,256, W1, W2, 512, bmid,512, 2048,512,256);
    gemm_t<2><<<dim3(32,4),256,0,stream>>>(bmid,512, Wb,256, out,256, 2048,256,512, nullptr, rig, maskp, cgres, idxp);
}